// Round 4
// baseline (1135.701 us; speedup 1.0000x reference)
//
#include <hip/hip_runtime.h>
#include <math.h>

#define N_NODES 20000
#define E_EDGES 320000
#define E_TOT   (E_EDGES + N_NODES)
#define IN_DIM  384
#define DIM     256
#define LAYERS  3
#define NEG_SLOPE 0.2f
#define LN_EPS 1e-5f

typedef unsigned short u16;
typedef unsigned int u32;
typedef __attribute__((ext_vector_type(8))) short short8;
typedef __attribute__((ext_vector_type(8))) __bf16 bf16x8;
typedef __attribute__((ext_vector_type(4))) float f32x4;

__device__ inline u16 f2bf(float f) {
    u32 u = __builtin_bit_cast(u32, f);
    return (u16)((u + 0x7fffu + ((u >> 16) & 1u)) >> 16);
}
__device__ inline float bf2f(u16 s) {
    u32 u = (u32)s << 16;
    return __builtin_bit_cast(float, u);
}
__device__ inline float4 cvt4(ushort4 u) {
    return make_float4(bf2f(u.x), bf2f(u.y), bf2f(u.z), bf2f(u.w));
}

__device__ inline f32x4 mfma_bf16(short8 a, short8 b, f32x4 c) {
    return __builtin_amdgcn_mfma_f32_16x16x32_bf16(
        __builtin_bit_cast(bf16x8, a), __builtin_bit_cast(bf16x8, b), c, 0, 0, 0);
}

__device__ inline void gl_lds16(const u16* g, u16* l) {
    __builtin_amdgcn_global_load_lds(
        (const __attribute__((address_space(1))) u32*)g,
        (__attribute__((address_space(3))) u32*)l, 16, 0, 0);
}

// ---------------- CSR build ----------------
__global__ void count_kernel(const int* __restrict__ ei, int* __restrict__ counts) {
    int e = blockIdx.x * 256 + threadIdx.x;
    if (e >= E_TOT) return;
    int d = (e < E_EDGES) ? ei[E_EDGES + e] : (e - E_EDGES);
    atomicAdd(&counts[d], 1);
}

__global__ __launch_bounds__(1024) void scan_kernel(const int* __restrict__ counts,
                                                    int* __restrict__ row_ptr) {
    __shared__ int sums[1024];
    const int t = threadIdx.x;
    const int CH = (N_NODES + 1023) / 1024;
    int base = t * CH;
    int local = 0;
    for (int i = 0; i < CH; ++i) {
        int idx = base + i;
        if (idx < N_NODES) local += counts[idx];
    }
    sums[t] = local;
    __syncthreads();
    for (int off = 1; off < 1024; off <<= 1) {
        int v = (t >= off) ? sums[t - off] : 0;
        __syncthreads();
        sums[t] += v;
        __syncthreads();
    }
    int run = (t == 0) ? 0 : sums[t - 1];
    for (int i = 0; i < CH; ++i) {
        int idx = base + i;
        if (idx < N_NODES) { row_ptr[idx] = run; run += counts[idx]; }
    }
    if (t == 1023) row_ptr[N_NODES] = sums[1023];
}

__global__ void scatter_kernel(const int* __restrict__ ei, const int* __restrict__ row_ptr,
                               int* __restrict__ cursor, int* __restrict__ csr_src) {
    int e = blockIdx.x * 256 + threadIdx.x;
    if (e >= E_TOT) return;
    int s, d;
    if (e < E_EDGES) { s = ei[e]; d = ei[E_EDGES + e]; }
    else { s = e - E_EDGES; d = s; }
    int pos = row_ptr[d] + atomicAdd(&cursor[d], 1);
    csr_src[pos] = s;
}

// ---------------- conversion kernels ----------------
__global__ void convert_bf16(const float* __restrict__ in, u16* __restrict__ out, int n4) {
    int i = blockIdx.x * 256 + threadIdx.x;
    if (i >= n4) return;
    float4 v = reinterpret_cast<const float4*>(in)[i];
    reinterpret_cast<ushort4*>(out)[i] =
        make_ushort4(f2bf(v.x), f2bf(v.y), f2bf(v.z), f2bf(v.w));
}

#define W_IN_ELEMS (IN_DIM * DIM)
#define W_LR_ELEMS (2 * DIM * DIM)
#define W_TOT (W_IN_ELEMS + LAYERS * W_LR_ELEMS)
__global__ void convert_weights(const float* __restrict__ w_in, const float* __restrict__ wl,
                                const float* __restrict__ wr, u16* __restrict__ out) {
    int idx = blockIdx.x * 256 + threadIdx.x;
    if (idx >= W_TOT) return;
    float v;
    if (idx < W_IN_ELEMS) {
        int n = idx / IN_DIM, k = idx % IN_DIM;
        v = w_in[k * DIM + n];
    } else {
        int j = idx - W_IN_ELEMS;
        int l = j / W_LR_ELEMS;
        int r = j % W_LR_ELEMS;
        int n = r >> 8, k = r & 255;
        const float* W = (n < DIM) ? wl : wr;
        v = W[l * DIM * DIM + k * DIM + (n & 255)];
    }
    out[idx] = f2bf(v);
}

// ---------------- bf16 MFMA GEMM, BK=64, double-buffered prefetch ----------------
// C = A (M x K bf16 row-major) @ B^T (B given as [ldc][K] bf16 row-major).
// 128x128 tile, 4 waves (2x2). Row = 8 x 16B blocks; stored_blk = blk ^ (row&7)
// (inverse XOR applied to the global source column so LDS dest stays linear).
#define BM 128
#define BN 128
#define BK 64
template <int K, int MODE>   // MODE 0: +bias, write C f32 + Cbf. MODE 1: Cbf only.
__global__ __launch_bounds__(256) void gemm_mfma(
    const u16* __restrict__ A, const u16* __restrict__ B,
    const float* __restrict__ bias,
    float* __restrict__ C, u16* __restrict__ Cbf,
    int M, int ldc) {
    __shared__ u16 lds[2][2][BM * BK];     // [buf][A=0/B=1], 16KB each, 64KB total
    const int tid = threadIdx.x;
    const int w = tid >> 6, lane = tid & 63;
    const int wm = w >> 1, wn = w & 1;
    const int bm = blockIdx.y * BM, bn = blockIdx.x * BN;
    const int fr = lane & 15, q = lane >> 4;

    f32x4 acc[4][4] = {};

    // staging geometry (per thread): chunk = i*256 + tid; row = chunk>>3, sblk = chunk&7
    const int s_row = tid >> 3, s_blk = tid & 7;        // within i-group offset row i*32
    constexpr int NT = K / BK;

    // prologue: stage tile 0 into buf 0
#pragma unroll
    for (int i = 0; i < 4; ++i) {
        int row = i * 32 + s_row;
        int gcol = ((s_blk ^ (row & 7)) << 3);
        int base = (i * 256 + (tid & ~63)) << 3;        // wave-uniform LDS base (u16)
        int ra = min(bm + row, M - 1);
        gl_lds16(A + (size_t)ra * K + gcol, &lds[0][0][base]);
        gl_lds16(B + (size_t)(bn + row) * K + gcol, &lds[0][1][base]);
    }
    __syncthreads();

    for (int t = 0; t < NT; ++t) {
        const int p = t & 1;
        if (t + 1 < NT) {
            const int k0 = (t + 1) * BK;
#pragma unroll
            for (int i = 0; i < 4; ++i) {
                int row = i * 32 + s_row;
                int gcol = ((s_blk ^ (row & 7)) << 3);
                int base = (i * 256 + (tid & ~63)) << 3;
                int ra = min(bm + row, M - 1);
                gl_lds16(A + (size_t)ra * K + k0 + gcol, &lds[p ^ 1][0][base]);
                gl_lds16(B + (size_t)(bn + row) * K + k0 + gcol, &lds[p ^ 1][1][base]);
            }
        }
        short8 a_f[2][4], b_f[2][4];
#pragma unroll
        for (int kk = 0; kk < 2; ++kk) {
#pragma unroll
            for (int mi = 0; mi < 4; ++mi) {
                int row = wm * 64 + mi * 16 + fr;
                a_f[kk][mi] = *reinterpret_cast<const short8*>(
                    &lds[p][0][row * BK + ((((kk << 2) + q) ^ (row & 7)) << 3)]);
            }
#pragma unroll
            for (int ni = 0; ni < 4; ++ni) {
                int row = wn * 64 + ni * 16 + fr;
                b_f[kk][ni] = *reinterpret_cast<const short8*>(
                    &lds[p][1][row * BK + ((((kk << 2) + q) ^ (row & 7)) << 3)]);
            }
        }
#pragma unroll
        for (int kk = 0; kk < 2; ++kk)
#pragma unroll
            for (int mi = 0; mi < 4; ++mi)
#pragma unroll
                for (int ni = 0; ni < 4; ++ni)
                    acc[mi][ni] = mfma_bf16(a_f[kk][mi], b_f[kk][ni], acc[mi][ni]);
        __syncthreads();
    }

    // epilogue: C/D layout col = lane&15, row = (lane>>4)*4 + reg
#pragma unroll
    for (int mi = 0; mi < 4; ++mi) {
#pragma unroll
        for (int r = 0; r < 4; ++r) {
            int row = bm + wm * 64 + mi * 16 + q * 4 + r;
            if (row >= M) continue;
#pragma unroll
            for (int ni = 0; ni < 4; ++ni) {
                int col = bn + wn * 64 + ni * 16 + fr;
                float v = acc[mi][ni][r];
                if (MODE == 0) {
                    v += bias[col];
                    C[(size_t)row * ldc + col] = v;
                }
                Cbf[(size_t)row * ldc + col] = f2bf(v);
            }
        }
    }
}

// ---------------- GATv2 edge aggregation + bias + LN + residual ----------------
// xlr_bf: [N][512] bf16 (xl | xr). One wave per node via work stealing.
// No-max softmax: logits are bounded (~|p|<10) by construction, f32 exp is safe.
template <bool LAST>
__global__ __launch_bounds__(256) void gat_edge(const u16* __restrict__ xlr_bf,
                                                const int* __restrict__ row_ptr,
                                                const int* __restrict__ csr_src,
                                                const float* __restrict__ att,
                                                const float* __restrict__ bias,
                                                const float* __restrict__ ln_g,
                                                const float* __restrict__ ln_b,
                                                float* __restrict__ h,
                                                u16* __restrict__ h_bf,
                                                float* __restrict__ out,
                                                int* __restrict__ ctr) {
    const int lane = threadIdx.x & 63;
    const int c4 = lane << 2;
    const float4 a4 = *reinterpret_cast<const float4*>(att + c4);
    const float4 b4 = *reinterpret_cast<const float4*>(bias + c4);
    const float4 g4 = *reinterpret_cast<const float4*>(ln_g + c4);
    const float4 lb4 = *reinterpret_cast<const float4*>(ln_b + c4);

    for (;;) {
        int node = 0;
        if (lane == 0) node = atomicAdd(ctr, 1);
        node = __shfl(node, 0);
        if (node >= N_NODES) return;

        const float4 xr4 = cvt4(*reinterpret_cast<const ushort4*>(
            xlr_bf + (size_t)node * 512 + 256 + c4));

        float sA = 0.f, sB = 0.f;
        float4 accA = make_float4(0.f, 0.f, 0.f, 0.f);
        float4 accB = make_float4(0.f, 0.f, 0.f, 0.f);

        const int e0 = row_ptr[node], e1 = row_ptr[node + 1];
        int e = e0;
        for (; e + 1 < e1; e += 2) {
            int srcA = csr_src[e], srcB = csr_src[e + 1];
            float4 xa = cvt4(*reinterpret_cast<const ushort4*>(xlr_bf + (size_t)srcA * 512 + c4));
            float4 xb = cvt4(*reinterpret_cast<const ushort4*>(xlr_bf + (size_t)srcB * 512 + c4));

            float vax = xa.x + xr4.x; vax = fmaxf(vax, NEG_SLOPE * vax);
            float vay = xa.y + xr4.y; vay = fmaxf(vay, NEG_SLOPE * vay);
            float vaz = xa.z + xr4.z; vaz = fmaxf(vaz, NEG_SLOPE * vaz);
            float vaw = xa.w + xr4.w; vaw = fmaxf(vaw, NEG_SLOPE * vaw);
            float pA = vax * a4.x + vay * a4.y + vaz * a4.z + vaw * a4.w;

            float vbx = xb.x + xr4.x; vbx = fmaxf(vbx, NEG_SLOPE * vbx);
            float vby = xb.y + xr4.y; vby = fmaxf(vby, NEG_SLOPE * vby);
            float vbz = xb.z + xr4.z; vbz = fmaxf(vbz, NEG_SLOPE * vbz);
            float vbw = xb.w + xr4.w; vbw = fmaxf(vbw, NEG_SLOPE * vbw);
            float pB = vbx * a4.x + vby * a4.y + vbz * a4.z + vbw * a4.w;

            pA += __shfl_xor(pA, 1); pB += __shfl_xor(pB, 1);
            pA += __shfl_xor(pA, 2); pB += __shfl_xor(pB, 2);
            pA += __shfl_xor(pA, 4); pB += __shfl_xor(pB, 4);
            pA += __shfl_xor(pA, 8); pB += __shfl_xor(pB, 8);

            float peA = __expf(pA);
            float peB = __expf(pB);
            sA += peA; sB += peB;
            accA.x = fmaf(peA, xa.x, accA.x);
            accA.y = fmaf(peA, xa.y, accA.y);
            accA.z = fmaf(peA, xa.z, accA.z);
            accA.w = fmaf(peA, xa.w, accA.w);
            accB.x = fmaf(peB, xb.x, accB.x);
            accB.y = fmaf(peB, xb.y, accB.y);
            accB.z = fmaf(peB, xb.z, accB.z);
            accB.w = fmaf(peB, xb.w, accB.w);
        }
        if (e < e1) {
            int src = csr_src[e];
            float4 xa = cvt4(*reinterpret_cast<const ushort4*>(xlr_bf + (size_t)src * 512 + c4));
            float vax = xa.x + xr4.x; vax = fmaxf(vax, NEG_SLOPE * vax);
            float vay = xa.y + xr4.y; vay = fmaxf(vay, NEG_SLOPE * vay);
            float vaz = xa.z + xr4.z; vaz = fmaxf(vaz, NEG_SLOPE * vaz);
            float vaw = xa.w + xr4.w; vaw = fmaxf(vaw, NEG_SLOPE * vaw);
            float pA = vax * a4.x + vay * a4.y + vaz * a4.z + vaw * a4.w;
            pA += __shfl_xor(pA, 1);
            pA += __shfl_xor(pA, 2);
            pA += __shfl_xor(pA, 4);
            pA += __shfl_xor(pA, 8);
            float peA = __expf(pA);
            sA += peA;
            accA.x = fmaf(peA, xa.x, accA.x);
            accA.y = fmaf(peA, xa.y, accA.y);
            accA.z = fmaf(peA, xa.z, accA.z);
            accA.w = fmaf(peA, xa.w, accA.w);
        }
        float s = sA + sB;
        float inv = 1.f / (s + 1e-16f);
        float ox = (accA.x + accB.x) * inv + b4.x;
        float oy = (accA.y + accB.y) * inv + b4.y;
        float oz = (accA.z + accB.z) * inv + b4.z;
        float ow = (accA.w + accB.w) * inv + b4.w;

        float lsum = ox + oy + oz + ow;
        float lsq  = ox * ox + oy * oy + oz * oz + ow * ow;
#pragma unroll
        for (int off = 1; off < 64; off <<= 1) {
            lsum += __shfl_xor(lsum, off);
            lsq  += __shfl_xor(lsq, off);
        }
        float mu = lsum * (1.f / 256.f);
        float var = lsq * (1.f / 256.f) - mu * mu;
        float rstd = rsqrtf(var + LN_EPS);
        float4 hv = *reinterpret_cast<const float4*>(h + (size_t)node * DIM + c4);
        hv.x += (ox - mu) * rstd * g4.x + lb4.x;
        hv.y += (oy - mu) * rstd * g4.y + lb4.y;
        hv.z += (oz - mu) * rstd * g4.z + lb4.z;
        hv.w += (ow - mu) * rstd * g4.w + lb4.w;

        if (LAST) {
            float nsq = hv.x * hv.x + hv.y * hv.y + hv.z * hv.z + hv.w * hv.w;
#pragma unroll
            for (int off = 1; off < 64; off <<= 1) nsq += __shfl_xor(nsq, off);
            float ninv = 1.f / fmaxf(sqrtf(nsq), 1e-12f);
            float4 o = make_float4(hv.x * ninv, hv.y * ninv, hv.z * ninv, hv.w * ninv);
            *reinterpret_cast<float4*>(out + (size_t)node * DIM + c4) = o;
        } else {
            *reinterpret_cast<float4*>(h + (size_t)node * DIM + c4) = hv;
            *reinterpret_cast<ushort4*>(h_bf + (size_t)node * DIM + c4) =
                make_ushort4(f2bf(hv.x), f2bf(hv.y), f2bf(hv.z), f2bf(hv.w));
        }
    }
}

extern "C" void kernel_launch(void* const* d_in, const int* in_sizes, int n_in,
                              void* d_out, int out_size, void* d_ws, size_t ws_size,
                              hipStream_t stream) {
    const float* x    = (const float*)d_in[0];
    const int*   ei   = (const int*)d_in[1];
    const float* w_in = (const float*)d_in[2];
    const float* b_in = (const float*)d_in[3];
    const float* wl   = (const float*)d_in[4];
    const float* wr   = (const float*)d_in[5];
    const float* att  = (const float*)d_in[6];
    const float* bias = (const float*)d_in[7];
    const float* ln_g = (const float*)d_in[8];
    const float* ln_b = (const float*)d_in[9];

    char* p = (char*)d_ws;
    float* h      = (float*)p;            p += (size_t)N_NODES * DIM * 4;
    u16*   h_bf   = (u16*)p;              p += (size_t)N_NODES * DIM * 2;
    u16*   xlr_bf = (u16*)p;              p += (size_t)N_NODES * 512 * 2;
    u16*   w_bf   = (u16*)p;              p += (size_t)W_TOT * 2;
    int* row_ptr  = (int*)p;              p += (N_NODES + 1) * 4;
    int* counts   = (int*)p;              p += N_NODES * 4;
    int* cursor   = (int*)p;              p += N_NODES * 4;
    int* ctrs     = (int*)p;              p += 4 * 4;
    int* csr_src  = (int*)p;

    u16* x_bf = xlr_bf;   // alias: x_bf only needed before the first layer GEMM

    // zero counts + cursor + ctrs in one memset (contiguous)
    hipMemsetAsync(counts, 0, sizeof(int) * (2 * N_NODES + 4), stream);
    count_kernel<<<(E_TOT + 255) / 256, 256, 0, stream>>>(ei, counts);
    scan_kernel<<<1, 1024, 0, stream>>>(counts, row_ptr);
    scatter_kernel<<<(E_TOT + 255) / 256, 256, 0, stream>>>(ei, row_ptr, cursor, csr_src);

    {
        int n4 = N_NODES * IN_DIM / 4;
        convert_bf16<<<(n4 + 255) / 256, 256, 0, stream>>>(x, x_bf, n4);
        convert_weights<<<(W_TOT + 255) / 256, 256, 0, stream>>>(w_in, wl, wr, w_bf);
    }

    gemm_mfma<IN_DIM, 0><<<dim3(DIM / BN, (N_NODES + BM - 1) / BM), 256, 0, stream>>>(
        x_bf, w_bf, b_in, h, h_bf, N_NODES, DIM);

    for (int l = 0; l < LAYERS; ++l) {
        const u16* wlr = w_bf + W_IN_ELEMS + (size_t)l * W_LR_ELEMS;
        gemm_mfma<DIM, 1><<<dim3(512 / BN, (N_NODES + BM - 1) / BM), 256, 0, stream>>>(
            h_bf, wlr, nullptr, nullptr, xlr_bf, N_NODES, 512);
        if (l < LAYERS - 1) {
            gat_edge<false><<<2048, 256, 0, stream>>>(
                xlr_bf, row_ptr, csr_src,
                att + (size_t)l * DIM, bias + (size_t)l * DIM,
                ln_g + (size_t)l * DIM, ln_b + (size_t)l * DIM,
                h, h_bf, nullptr, &ctrs[l]);
        } else {
            gat_edge<true><<<2048, 256, 0, stream>>>(
                xlr_bf, row_ptr, csr_src,
                att + (size_t)l * DIM, bias + (size_t)l * DIM,
                ln_g + (size_t)l * DIM, ln_b + (size_t)l * DIM,
                h, h_bf, (float*)d_out, &ctrs[l]);
        }
    }
}

// Round 5
// 257.472 us; speedup vs baseline: 4.4110x; 4.4110x over previous
//
#include <hip/hip_runtime.h>
#include <math.h>

#define N_NODES 20000
#define E_EDGES 320000
#define E_TOT   (E_EDGES + N_NODES)
#define IN_DIM  384
#define DIM     256
#define LAYERS  3
#define NEG_SLOPE 0.2f
#define LN_EPS 1e-5f

typedef unsigned short u16;
typedef unsigned int u32;
typedef __attribute__((ext_vector_type(8))) short short8;
typedef __attribute__((ext_vector_type(8))) __bf16 bf16x8;
typedef __attribute__((ext_vector_type(4))) float f32x4;

__device__ inline u16 f2bf(float f) {
    u32 u = __builtin_bit_cast(u32, f);
    return (u16)((u + 0x7fffu + ((u >> 16) & 1u)) >> 16);
}
__device__ inline float bf2f(u16 s) {
    u32 u = (u32)s << 16;
    return __builtin_bit_cast(float, u);
}
__device__ inline float4 cvt4(ushort4 u) {
    return make_float4(bf2f(u.x), bf2f(u.y), bf2f(u.z), bf2f(u.w));
}

__device__ inline f32x4 mfma_bf16(short8 a, short8 b, f32x4 c) {
    return __builtin_amdgcn_mfma_f32_16x16x32_bf16(
        __builtin_bit_cast(bf16x8, a), __builtin_bit_cast(bf16x8, b), c, 0, 0, 0);
}

__device__ inline void gl_lds16(const u16* g, u16* l) {
    __builtin_amdgcn_global_load_lds(
        (const __attribute__((address_space(1))) u32*)g,
        (__attribute__((address_space(3))) u32*)l, 16, 0, 0);
}

// ---------------- CSR build ----------------
__global__ void count_kernel(const int* __restrict__ ei, int* __restrict__ counts) {
    int e = blockIdx.x * 256 + threadIdx.x;
    if (e >= E_TOT) return;
    int d = (e < E_EDGES) ? ei[E_EDGES + e] : (e - E_EDGES);
    atomicAdd(&counts[d], 1);
}

__global__ __launch_bounds__(1024) void scan_kernel(const int* __restrict__ counts,
                                                    int* __restrict__ row_ptr) {
    __shared__ int sums[1024];
    const int t = threadIdx.x;
    const int CH = (N_NODES + 1023) / 1024;
    int base = t * CH;
    int local = 0;
    for (int i = 0; i < CH; ++i) {
        int idx = base + i;
        if (idx < N_NODES) local += counts[idx];
    }
    sums[t] = local;
    __syncthreads();
    for (int off = 1; off < 1024; off <<= 1) {
        int v = (t >= off) ? sums[t - off] : 0;
        __syncthreads();
        sums[t] += v;
        __syncthreads();
    }
    int run = (t == 0) ? 0 : sums[t - 1];
    for (int i = 0; i < CH; ++i) {
        int idx = base + i;
        if (idx < N_NODES) { row_ptr[idx] = run; run += counts[idx]; }
    }
    if (t == 1023) row_ptr[N_NODES] = sums[1023];
}

__global__ void scatter_kernel(const int* __restrict__ ei, const int* __restrict__ row_ptr,
                               int* __restrict__ cursor, int* __restrict__ csr_src) {
    int e = blockIdx.x * 256 + threadIdx.x;
    if (e >= E_TOT) return;
    int s, d;
    if (e < E_EDGES) { s = ei[e]; d = ei[E_EDGES + e]; }
    else { s = e - E_EDGES; d = s; }
    int pos = row_ptr[d] + atomicAdd(&cursor[d], 1);
    csr_src[pos] = s;
}

// ---------------- conversion kernels ----------------
__global__ void convert_bf16(const float* __restrict__ in, u16* __restrict__ out, int n4) {
    int i = blockIdx.x * 256 + threadIdx.x;
    if (i >= n4) return;
    float4 v = reinterpret_cast<const float4*>(in)[i];
    reinterpret_cast<ushort4*>(out)[i] =
        make_ushort4(f2bf(v.x), f2bf(v.y), f2bf(v.z), f2bf(v.w));
}

#define W_IN_ELEMS (IN_DIM * DIM)
#define W_LR_ELEMS (2 * DIM * DIM)
#define W_TOT (W_IN_ELEMS + LAYERS * W_LR_ELEMS)
__global__ void convert_weights(const float* __restrict__ w_in, const float* __restrict__ wl,
                                const float* __restrict__ wr, u16* __restrict__ out) {
    int idx = blockIdx.x * 256 + threadIdx.x;
    if (idx >= W_TOT) return;
    float v;
    if (idx < W_IN_ELEMS) {
        int n = idx / IN_DIM, k = idx % IN_DIM;
        v = w_in[k * DIM + n];
    } else {
        int j = idx - W_IN_ELEMS;
        int l = j / W_LR_ELEMS;
        int r = j % W_LR_ELEMS;
        int n = r >> 8, k = r & 255;
        const float* W = (n < DIM) ? wl : wr;
        v = W[l * DIM * DIM + k * DIM + (n & 255)];
    }
    out[idx] = f2bf(v);
}

// ---------------- bf16 MFMA GEMM, BK=64, double-buffered prefetch ----------------
#define BM 128
#define BN 128
#define BK 64
template <int K, int MODE>   // MODE 0: +bias, write C f32 + Cbf. MODE 1: Cbf only.
__global__ __launch_bounds__(256) void gemm_mfma(
    const u16* __restrict__ A, const u16* __restrict__ B,
    const float* __restrict__ bias,
    float* __restrict__ C, u16* __restrict__ Cbf,
    int M, int ldc) {
    __shared__ u16 lds[2][2][BM * BK];
    const int tid = threadIdx.x;
    const int w = tid >> 6, lane = tid & 63;
    const int wm = w >> 1, wn = w & 1;
    const int bm = blockIdx.y * BM, bn = blockIdx.x * BN;
    const int fr = lane & 15, q = lane >> 4;

    f32x4 acc[4][4] = {};

    const int s_row = tid >> 3, s_blk = tid & 7;
    constexpr int NT = K / BK;

#pragma unroll
    for (int i = 0; i < 4; ++i) {
        int row = i * 32 + s_row;
        int gcol = ((s_blk ^ (row & 7)) << 3);
        int base = (i * 256 + (tid & ~63)) << 3;
        int ra = min(bm + row, M - 1);
        gl_lds16(A + (size_t)ra * K + gcol, &lds[0][0][base]);
        gl_lds16(B + (size_t)(bn + row) * K + gcol, &lds[0][1][base]);
    }
    __syncthreads();

    for (int t = 0; t < NT; ++t) {
        const int p = t & 1;
        if (t + 1 < NT) {
            const int k0 = (t + 1) * BK;
#pragma unroll
            for (int i = 0; i < 4; ++i) {
                int row = i * 32 + s_row;
                int gcol = ((s_blk ^ (row & 7)) << 3);
                int base = (i * 256 + (tid & ~63)) << 3;
                int ra = min(bm + row, M - 1);
                gl_lds16(A + (size_t)ra * K + k0 + gcol, &lds[p ^ 1][0][base]);
                gl_lds16(B + (size_t)(bn + row) * K + k0 + gcol, &lds[p ^ 1][1][base]);
            }
        }
        short8 a_f[2][4], b_f[2][4];
#pragma unroll
        for (int kk = 0; kk < 2; ++kk) {
#pragma unroll
            for (int mi = 0; mi < 4; ++mi) {
                int row = wm * 64 + mi * 16 + fr;
                a_f[kk][mi] = *reinterpret_cast<const short8*>(
                    &lds[p][0][row * BK + ((((kk << 2) + q) ^ (row & 7)) << 3)]);
            }
#pragma unroll
            for (int ni = 0; ni < 4; ++ni) {
                int row = wn * 64 + ni * 16 + fr;
                b_f[kk][ni] = *reinterpret_cast<const short8*>(
                    &lds[p][1][row * BK + ((((kk << 2) + q) ^ (row & 7)) << 3)]);
            }
        }
#pragma unroll
        for (int kk = 0; kk < 2; ++kk)
#pragma unroll
            for (int mi = 0; mi < 4; ++mi)
#pragma unroll
                for (int ni = 0; ni < 4; ++ni)
                    acc[mi][ni] = mfma_bf16(a_f[kk][mi], b_f[kk][ni], acc[mi][ni]);
        __syncthreads();
    }

#pragma unroll
    for (int mi = 0; mi < 4; ++mi) {
#pragma unroll
        for (int r = 0; r < 4; ++r) {
            int row = bm + wm * 64 + mi * 16 + q * 4 + r;
            if (row >= M) continue;
#pragma unroll
            for (int ni = 0; ni < 4; ++ni) {
                int col = bn + wn * 64 + ni * 16 + fr;
                float v = acc[mi][ni][r];
                if (MODE == 0) {
                    v += bias[col];
                    C[(size_t)row * ldc + col] = v;
                }
                Cbf[(size_t)row * ldc + col] = f2bf(v);
            }
        }
    }
}

// ---------------- GATv2 edge aggregation + bias + LN + residual ----------------
// xlr_bf: [N][512] bf16 (xl | xr). One wave per node, STATIC mapping
// (work-stealing regressed 7x: single-address cross-XCD atomics serialize).
// No-max softmax: logits bounded (|p| < ~10) by construction; validated vs ref.
template <bool LAST>
__global__ __launch_bounds__(256) void gat_edge(const u16* __restrict__ xlr_bf,
                                                const int* __restrict__ row_ptr,
                                                const int* __restrict__ csr_src,
                                                const float* __restrict__ att,
                                                const float* __restrict__ bias,
                                                const float* __restrict__ ln_g,
                                                const float* __restrict__ ln_b,
                                                float* __restrict__ h,
                                                u16* __restrict__ h_bf,
                                                float* __restrict__ out) {
    const int wave = threadIdx.x >> 6;
    const int lane = threadIdx.x & 63;
    const int node = blockIdx.x * 4 + wave;
    if (node >= N_NODES) return;
    const int c4 = lane << 2;

    const float4 a4  = *reinterpret_cast<const float4*>(att + c4);
    const float4 xr4 = cvt4(*reinterpret_cast<const ushort4*>(
        xlr_bf + (size_t)node * 512 + 256 + c4));

    float sA = 0.f, sB = 0.f;
    float4 accA = make_float4(0.f, 0.f, 0.f, 0.f);
    float4 accB = make_float4(0.f, 0.f, 0.f, 0.f);

    const int e0 = row_ptr[node], e1 = row_ptr[node + 1];
    int e = e0;
    for (; e + 1 < e1; e += 2) {
        int srcA = csr_src[e], srcB = csr_src[e + 1];
        float4 xa = cvt4(*reinterpret_cast<const ushort4*>(xlr_bf + (size_t)srcA * 512 + c4));
        float4 xb = cvt4(*reinterpret_cast<const ushort4*>(xlr_bf + (size_t)srcB * 512 + c4));

        float vax = xa.x + xr4.x; vax = fmaxf(vax, NEG_SLOPE * vax);
        float vay = xa.y + xr4.y; vay = fmaxf(vay, NEG_SLOPE * vay);
        float vaz = xa.z + xr4.z; vaz = fmaxf(vaz, NEG_SLOPE * vaz);
        float vaw = xa.w + xr4.w; vaw = fmaxf(vaw, NEG_SLOPE * vaw);
        float pA = vax * a4.x + vay * a4.y + vaz * a4.z + vaw * a4.w;

        float vbx = xb.x + xr4.x; vbx = fmaxf(vbx, NEG_SLOPE * vbx);
        float vby = xb.y + xr4.y; vby = fmaxf(vby, NEG_SLOPE * vby);
        float vbz = xb.z + xr4.z; vbz = fmaxf(vbz, NEG_SLOPE * vbz);
        float vbw = xb.w + xr4.w; vbw = fmaxf(vbw, NEG_SLOPE * vbw);
        float pB = vbx * a4.x + vby * a4.y + vbz * a4.z + vbw * a4.w;

        pA += __shfl_xor(pA, 1); pB += __shfl_xor(pB, 1);
        pA += __shfl_xor(pA, 2); pB += __shfl_xor(pB, 2);
        pA += __shfl_xor(pA, 4); pB += __shfl_xor(pB, 4);
        pA += __shfl_xor(pA, 8); pB += __shfl_xor(pB, 8);

        float peA = __expf(pA);
        float peB = __expf(pB);
        sA += peA; sB += peB;
        accA.x = fmaf(peA, xa.x, accA.x);
        accA.y = fmaf(peA, xa.y, accA.y);
        accA.z = fmaf(peA, xa.z, accA.z);
        accA.w = fmaf(peA, xa.w, accA.w);
        accB.x = fmaf(peB, xb.x, accB.x);
        accB.y = fmaf(peB, xb.y, accB.y);
        accB.z = fmaf(peB, xb.z, accB.z);
        accB.w = fmaf(peB, xb.w, accB.w);
    }
    if (e < e1) {
        int src = csr_src[e];
        float4 xa = cvt4(*reinterpret_cast<const ushort4*>(xlr_bf + (size_t)src * 512 + c4));
        float vax = xa.x + xr4.x; vax = fmaxf(vax, NEG_SLOPE * vax);
        float vay = xa.y + xr4.y; vay = fmaxf(vay, NEG_SLOPE * vay);
        float vaz = xa.z + xr4.z; vaz = fmaxf(vaz, NEG_SLOPE * vaz);
        float vaw = xa.w + xr4.w; vaw = fmaxf(vaw, NEG_SLOPE * vaw);
        float pA = vax * a4.x + vay * a4.y + vaz * a4.z + vaw * a4.w;
        pA += __shfl_xor(pA, 1);
        pA += __shfl_xor(pA, 2);
        pA += __shfl_xor(pA, 4);
        pA += __shfl_xor(pA, 8);
        float peA = __expf(pA);
        sA += peA;
        accA.x = fmaf(peA, xa.x, accA.x);
        accA.y = fmaf(peA, xa.y, accA.y);
        accA.z = fmaf(peA, xa.z, accA.z);
        accA.w = fmaf(peA, xa.w, accA.w);
    }
    float s = sA + sB;
    float inv = 1.f / (s + 1e-16f);
    const float4 b4 = *reinterpret_cast<const float4*>(bias + c4);
    float ox = (accA.x + accB.x) * inv + b4.x;
    float oy = (accA.y + accB.y) * inv + b4.y;
    float oz = (accA.z + accB.z) * inv + b4.z;
    float ow = (accA.w + accB.w) * inv + b4.w;

    float lsum = ox + oy + oz + ow;
    float lsq  = ox * ox + oy * oy + oz * oz + ow * ow;
#pragma unroll
    for (int off = 1; off < 64; off <<= 1) {
        lsum += __shfl_xor(lsum, off);
        lsq  += __shfl_xor(lsq, off);
    }
    float mu = lsum * (1.f / 256.f);
    float var = lsq * (1.f / 256.f) - mu * mu;
    float rstd = rsqrtf(var + LN_EPS);
    const float4 g4  = *reinterpret_cast<const float4*>(ln_g + c4);
    const float4 lb4 = *reinterpret_cast<const float4*>(ln_b + c4);
    float4 hv = *reinterpret_cast<const float4*>(h + (size_t)node * DIM + c4);
    hv.x += (ox - mu) * rstd * g4.x + lb4.x;
    hv.y += (oy - mu) * rstd * g4.y + lb4.y;
    hv.z += (oz - mu) * rstd * g4.z + lb4.z;
    hv.w += (ow - mu) * rstd * g4.w + lb4.w;

    if (LAST) {
        float nsq = hv.x * hv.x + hv.y * hv.y + hv.z * hv.z + hv.w * hv.w;
#pragma unroll
        for (int off = 1; off < 64; off <<= 1) nsq += __shfl_xor(nsq, off);
        float ninv = 1.f / fmaxf(sqrtf(nsq), 1e-12f);
        float4 o = make_float4(hv.x * ninv, hv.y * ninv, hv.z * ninv, hv.w * ninv);
        *reinterpret_cast<float4*>(out + (size_t)node * DIM + c4) = o;
    } else {
        *reinterpret_cast<float4*>(h + (size_t)node * DIM + c4) = hv;
        *reinterpret_cast<ushort4*>(h_bf + (size_t)node * DIM + c4) =
            make_ushort4(f2bf(hv.x), f2bf(hv.y), f2bf(hv.z), f2bf(hv.w));
    }
}

extern "C" void kernel_launch(void* const* d_in, const int* in_sizes, int n_in,
                              void* d_out, int out_size, void* d_ws, size_t ws_size,
                              hipStream_t stream) {
    const float* x    = (const float*)d_in[0];
    const int*   ei   = (const int*)d_in[1];
    const float* w_in = (const float*)d_in[2];
    const float* b_in = (const float*)d_in[3];
    const float* wl   = (const float*)d_in[4];
    const float* wr   = (const float*)d_in[5];
    const float* att  = (const float*)d_in[6];
    const float* bias = (const float*)d_in[7];
    const float* ln_g = (const float*)d_in[8];
    const float* ln_b = (const float*)d_in[9];

    char* p = (char*)d_ws;
    float* h      = (float*)p;            p += (size_t)N_NODES * DIM * 4;
    u16*   h_bf   = (u16*)p;              p += (size_t)N_NODES * DIM * 2;
    u16*   xlr_bf = (u16*)p;              p += (size_t)N_NODES * 512 * 2;
    u16*   w_bf   = (u16*)p;              p += (size_t)W_TOT * 2;
    int* row_ptr  = (int*)p;              p += (N_NODES + 1) * 4;
    int* counts   = (int*)p;              p += N_NODES * 4;
    int* cursor   = (int*)p;              p += N_NODES * 4;
    int* csr_src  = (int*)p;

    u16* x_bf = xlr_bf;   // alias: x_bf only needed before the first layer GEMM

    hipMemsetAsync(counts, 0, sizeof(int) * 2 * N_NODES, stream);
    count_kernel<<<(E_TOT + 255) / 256, 256, 0, stream>>>(ei, counts);
    scan_kernel<<<1, 1024, 0, stream>>>(counts, row_ptr);
    scatter_kernel<<<(E_TOT + 255) / 256, 256, 0, stream>>>(ei, row_ptr, cursor, csr_src);

    {
        int n4 = N_NODES * IN_DIM / 4;
        convert_bf16<<<(n4 + 255) / 256, 256, 0, stream>>>(x, x_bf, n4);
        convert_weights<<<(W_TOT + 255) / 256, 256, 0, stream>>>(w_in, wl, wr, w_bf);
    }

    gemm_mfma<IN_DIM, 0><<<dim3(DIM / BN, (N_NODES + BM - 1) / BM), 256, 0, stream>>>(
        x_bf, w_bf, b_in, h, h_bf, N_NODES, DIM);

    for (int l = 0; l < LAYERS; ++l) {
        const u16* wlr = w_bf + W_IN_ELEMS + (size_t)l * W_LR_ELEMS;
        gemm_mfma<DIM, 1><<<dim3(512 / BN, (N_NODES + BM - 1) / BM), 256, 0, stream>>>(
            h_bf, wlr, nullptr, nullptr, xlr_bf, N_NODES, 512);
        if (l < LAYERS - 1) {
            gat_edge<false><<<(N_NODES + 3) / 4, 256, 0, stream>>>(
                xlr_bf, row_ptr, csr_src,
                att + (size_t)l * DIM, bias + (size_t)l * DIM,
                ln_g + (size_t)l * DIM, ln_b + (size_t)l * DIM,
                h, h_bf, nullptr);
        } else {
            gat_edge<true><<<(N_NODES + 3) / 4, 256, 0, stream>>>(
                xlr_bf, row_ptr, csr_src,
                att + (size_t)l * DIM, bias + (size_t)l * DIM,
                ln_g + (size_t)l * DIM, ln_b + (size_t)l * DIM,
                h, h_bf, (float*)d_out);
        }
    }
}